// Round 17
// baseline (152.899 us; speedup 1.0000x reference)
//
#include <hip/hip_runtime.h>
#include <math.h>

typedef float f32x4 __attribute__((ext_vector_type(4)));
typedef __attribute__((ext_vector_type(8))) _Float16 f16x8;
typedef __attribute__((ext_vector_type(4))) _Float16 f16x4;

#define DD 256
#define DH 128
#define NSPLIT 2
#define TROWS 64  // rows per block tile

// ---------------------------------------------------------------------------
// K0 (merged): blocks 0..15: W1 -> f16 MFMA B-fragment order
//   w1f[((kt*8+nt)*64+l)*8+j] = f16(W1[kt*32+(l>>4)*8+j][nt*16+(l&15)])
// blocks 16..: segment boundaries (batch sorted).
// ---------------------------------------------------------------------------
__global__ void ap_setup(const float* __restrict__ W1, _Float16* __restrict__ w1f,
                         const int* __restrict__ batch, int* __restrict__ start,
                         int nrows, int bseg) {
  const int bid = blockIdx.x;
  if (bid < 16) {
    int t = bid * 256 + threadIdx.x;  // 0..4095
    int l = t & 63;
    int tile = t >> 6;  // kt*8 + nt
    int kt = tile >> 3, nt = tile & 7;
    int kbase = kt * 32 + (l >> 4) * 8;
    int col = nt * 16 + (l & 15);
#pragma unroll
    for (int j = 0; j < 8; ++j) {
      w1f[t * 8 + j] = (_Float16)W1[(kbase + j) * DH + col];
    }
  } else {
    int i = (bid - 16) * 256 + threadIdx.x;
    if (i >= nrows) return;
    int c = batch[i];
    int p = (i == 0) ? -1 : batch[i - 1];
    for (int b = p + 1; b <= c; ++b) start[b] = i;
    if (i == nrows - 1) {
      for (int b = c + 1; b <= bseg; ++b) start[b] = nrows;
    }
  }
}

// ---------------------------------------------------------------------------
// K2: fused, block = (segment, piece). Round-16 pipeline (f16-only MLP,
// double-buffered x tile, ONE barrier/tile) with the B-fragment LDS stream
// (256 KB/tile = 73% of LDS traffic) moved to REGISTERS:
//  - __launch_bounds__(512,1): 1 block/CU -> 2 waves/SIMD -> 256-VGPR cap
//    (rounds 8/9/14 spilled because k=2 caps at 128).
//  - MFMA wave mapping 2nt x 2rg (np=wv&3, rgp=wv>>2): Breg = 16 f16x8
//    = 64 VGPR only; LDS/tile 352 -> 160 KB.
//  - epilogue: 4 per-row partials praw[4][64], summed at softmax.
// Load/pool unchanged: coalesced (lane=chunk), pooling from live xcol regs.
// Per-piece online max (shift cancels except the 1e-8 term, ~1e-13 rel).
// Deterministic: fixed-order reductions, no fp atomics.
// ---------------------------------------------------------------------------
__global__ __launch_bounds__(512, 1)
void ap_fused(const float* __restrict__ x, const _Float16* __restrict__ w1f,
              const float* __restrict__ b1, const float* __restrict__ W2,
              const float* __restrict__ b2, const int* __restrict__ start,
              float* __restrict__ pooledPart, float* __restrict__ mPart,
              float* __restrict__ swPart, int nrows) {
  __shared__ __align__(16) _Float16 xsh[2][TROWS * 256];  // 2x32 KB f16 tiles
  __shared__ float praw[2][4][TROWS];                     // 4 np-partials/row
  __shared__ float swArr[8];

  const int tid = threadIdx.x;
  const int wv = tid >> 6;    // 0..7
  const int np = wv & 3;      // nt-pair: cols np*32 .. +32
  const int rgp = wv >> 2;    // row-group pair: rows rgp*32 .. +32
  const int l = tid & 63;
  const int l15 = l & 15, lhi = l >> 4;

  const int bi = blockIdx.x;
  const int b = bi >> 1;
  const int q = bi & (NSPLIT - 1);
  const int s0 = start[b], e0 = start[b + 1];
  const int cnt = e0 - s0;
  const int L = (cnt + NSPLIT - 1) >> 1;
  const int s = s0 + q * L;
  int pe = s + L;
  if (pe > e0) pe = e0;
  const int e = pe;
  const int ce = (e > 0) ? (e - 1) : 0;  // safe clamp row

  // ---- B fragments -> registers (16 frags = 64 VGPR), from L2 ----
  f16x8 Breg[16];  // [kt*2 + nt2], wave's nt = np*2 + nt2
#pragma unroll
  for (int kt = 0; kt < 8; ++kt) {
#pragma unroll
    for (int nt2 = 0; nt2 < 2; ++nt2) {
      Breg[kt * 2 + nt2] =
          *((const f16x8*)w1f + (size_t)(kt * 8 + np * 2 + nt2) * 64 + l);
    }
  }

  float b1f[2], w2f[2];
#pragma unroll
  for (int nt2 = 0; nt2 < 2; ++nt2) {
    const int idx = (np * 2 + nt2) * 16 + l15;
    b1f[nt2] = b1[idx];
    w2f[nt2] = W2[idx];
  }
  const float bb = *b2;
  const float NI = -__builtin_inff();

  f32x4 accp = {0.f, 0.f, 0.f, 0.f};  // lane-local pooled chunk (cols l*4..)
  float m = NI;
  float swv = 0.f;

  // prologue: load tile0 rows (coalesced: lane l = chunk l), cvt+write xs[0]
  f32x4 xcol[8], xnext[8];
#pragma unroll
  for (int i = 0; i < 8; ++i) {
    int grow = s + wv * 8 + i;
    if (grow > ce) grow = ce;
    if (grow < 0) grow = 0;
    xcol[i] = *(const f32x4*)(x + (size_t)grow * DD + l * 4);
  }
#pragma unroll
  for (int i = 0; i < 8; ++i) {
    const int R = wv * 8 + i;
    const int gp = l ^ ((R & 7) << 1);
    f16x4 h4;
#pragma unroll
    for (int j = 0; j < 4; ++j) h4[j] = (_Float16)xcol[i][j];
    *(f16x4*)(xsh[0] + (size_t)(R * 64 + gp) * 4) = h4;
  }
  __syncthreads();  // xs[0] ready

  int buf = 0;
  for (int t0 = s; t0 < e; t0 += TROWS) {
    const bool hasNext = (t0 + TROWS < e);

    // ---- (1) prefetch next tile rows ----
    if (hasNext) {
#pragma unroll
      for (int i = 0; i < 8; ++i) {
        int grow = t0 + TROWS + wv * 8 + i;
        if (grow > ce) grow = ce;
        xnext[i] = *(const f32x4*)(x + (size_t)grow * DD + l * 4);
      }
    }

    // ---- (2) MFMA: A from xs[buf] (2 row-groups), B from registers ----
    f32x4 acc[2][2];
#pragma unroll
    for (int rg2 = 0; rg2 < 2; ++rg2)
#pragma unroll
      for (int nt2 = 0; nt2 < 2; ++nt2) acc[rg2][nt2] = f32x4{0.f, 0.f, 0.f, 0.f};
#pragma unroll
    for (int kt = 0; kt < 8; ++kt) {
#pragma unroll
      for (int rg2 = 0; rg2 < 2; ++rg2) {
        const int Rr = rgp * 32 + rg2 * 16 + l15;
        const int gp = (kt * 8 + lhi * 2) ^ ((Rr & 7) << 1);
        const f16x8 ah = *(const f16x8*)(xsh[buf] + (size_t)(Rr * 64 + gp) * 4);
        acc[rg2][0] =
            __builtin_amdgcn_mfma_f32_16x16x32_f16(ah, Breg[kt * 2 + 0], acc[rg2][0], 0, 0, 0);
        acc[rg2][1] =
            __builtin_amdgcn_mfma_f32_16x16x32_f16(ah, Breg[kt * 2 + 1], acc[rg2][1], 0, 0, 0);
      }
    }

    // ---- (3) epilogue: relu+b1, dot W2 (wave's 32 cols), reduce l15 ----
    float pr[2][4];
#pragma unroll
    for (int rg2 = 0; rg2 < 2; ++rg2) {
#pragma unroll
      for (int r = 0; r < 4; ++r) {
        float t = fmaxf(acc[rg2][0][r] + b1f[0], 0.f) * w2f[0] +
                  fmaxf(acc[rg2][1][r] + b1f[1], 0.f) * w2f[1];
        pr[rg2][r] = t;
      }
    }
#pragma unroll
    for (int mm = 1; mm < 16; mm <<= 1) {
#pragma unroll
      for (int rg2 = 0; rg2 < 2; ++rg2)
#pragma unroll
        for (int r = 0; r < 4; ++r) pr[rg2][r] += __shfl_xor(pr[rg2][r], mm, 64);
    }
    if (l15 == 0) {
#pragma unroll
      for (int rg2 = 0; rg2 < 2; ++rg2)
#pragma unroll
        for (int r = 0; r < 4; ++r)
          praw[buf][np][rgp * 32 + rg2 * 16 + lhi * 4 + r] = pr[rg2][r];
    }

    // ---- (4) convert + write NEXT tile into xs[buf^1] (overlaps MFMA) ----
    if (hasNext) {
#pragma unroll
      for (int i = 0; i < 8; ++i) {
        const int R = wv * 8 + i;
        const int gp = l ^ ((R & 7) << 1);
        f16x4 h4;
#pragma unroll
        for (int j = 0; j < 4; ++j) h4[j] = (_Float16)xnext[i][j];
        *(f16x4*)(xsh[buf ^ 1] + (size_t)(R * 64 + gp) * 4) = h4;
      }
    }

    __syncthreads();  // (5) the ONE barrier per tile

    // ---- (6) block-uniform online softmax over the 64 tile rows ----
    const float tot = (t0 + l < e)
                          ? (praw[buf][0][l] + praw[buf][1][l] +
                             praw[buf][2][l] + praw[buf][3][l] + bb)
                          : NI;
    float tv = tot;
#pragma unroll
    for (int mm = 1; mm < 64; mm <<= 1) tv = fmaxf(tv, __shfl_xor(tv, mm, 64));
    const float nm = fmaxf(m, tv);       // row t0 valid -> finite
    const float factor = expf(m - nm);   // first tile: exp(-inf) = 0
    m = nm;
    accp *= factor;
    swv *= factor;

    // ---- (7) pooling from the LIVE xcol fp32 registers ----
#pragma unroll
    for (int i = 0; i < 8; ++i) {
      const int R = wv * 8 + i;
      const float wi = expf(__shfl(tot, R, 64) - m);  // invalid row -> 0
      swv += wi;
      accp += wi * xcol[i];
    }
#pragma unroll
    for (int i = 0; i < 8; ++i) xcol[i] = xnext[i];
    buf ^= 1;
  }

  // ---- combine 8 wave partials (m is block-uniform), write piece ----
  __syncthreads();                       // xs free; alias xsh as pooled
  float* pooled = (float*)xsh;           // 8x256 f32 = 8 KB
  *(f32x4*)(pooled + (size_t)(wv * 256 + l * 4)) = accp;
  if (l == 0) swArr[wv] = swv;
  __syncthreads();
  if (tid < 64) {
    float sum_w = 0.f;
#pragma unroll
    for (int p = 0; p < 8; ++p) sum_w += swArr[p];
    const f32x4* pw = (const f32x4*)pooled;
    f32x4 v = ((pw[0 * 64 + tid] + pw[1 * 64 + tid]) +
               (pw[2 * 64 + tid] + pw[3 * 64 + tid]));
    f32x4 w = ((pw[4 * 64 + tid] + pw[5 * 64 + tid]) +
               (pw[6 * 64 + tid] + pw[7 * 64 + tid]));
    *(f32x4*)(pooledPart + (size_t)bi * DD + tid * 4) = v + w;
    if (tid == 0) { mPart[bi] = m; swPart[bi] = sum_w; }
  }
}

// ---------------------------------------------------------------------------
// K3: merge the NSPLIT piece partials per segment (fixed order), scale, write.
// ---------------------------------------------------------------------------
__global__ __launch_bounds__(64)
void ap_final(const float* __restrict__ pooledPart, const float* __restrict__ mPart,
              const float* __restrict__ swPart, const int* __restrict__ start,
              float* __restrict__ out, int nrows) {
  const int b = blockIdx.x;
  const int tid = threadIdx.x;
  const float NI = -__builtin_inff();
  float mq[NSPLIT];
#pragma unroll
  for (int qv = 0; qv < NSPLIT; ++qv) mq[qv] = mPart[b * NSPLIT + qv];
  float m_f = NI;
#pragma unroll
  for (int qv = 0; qv < NSPLIT; ++qv) m_f = fmaxf(m_f, mq[qv]);
  float fac[NSPLIT];
  float sum_w = 0.f;
#pragma unroll
  for (int qv = 0; qv < NSPLIT; ++qv) {
    fac[qv] = (mq[qv] == NI) ? 0.f : expf(mq[qv] - m_f);
    sum_w += swPart[b * NSPLIT + qv] * fac[qv];
  }
  const int cnt = start[b + 1] - start[b];
  const float cntf = (float)(cnt > 0 ? cnt : 1);
  const float scale = 1.0f / (((sum_w / cntf) * (float)nrows + 1e-8f) * cntf);
  f32x4 r = f32x4{0.f, 0.f, 0.f, 0.f};
#pragma unroll
  for (int qv = 0; qv < NSPLIT; ++qv) {
    r += ((const f32x4*)(pooledPart + (size_t)(b * NSPLIT + qv) * DD))[tid] * fac[qv];
  }
  r *= scale;
  *(f32x4*)(out + (size_t)b * DD + tid * 4) = r;
}

extern "C" void kernel_launch(void* const* d_in, const int* in_sizes, int n_in,
                              void* d_out, int out_size, void* d_ws, size_t ws_size,
                              hipStream_t stream) {
  const float* x     = (const float*)d_in[0];
  const int*   batch = (const int*)d_in[1];
  const float* W1    = (const float*)d_in[2];
  const float* b1    = (const float*)d_in[3];
  const float* W2    = (const float*)d_in[4];
  const float* b2    = (const float*)d_in[5];
  float* out = (float*)d_out;

  const int nrows = in_sizes[1];
  const int bseg = out_size / DD;

  // workspace layout (16B-aligned)
  float* pooledPart = (float*)d_ws;                        // bseg*2*256 f32
  float* mPart  = pooledPart + (size_t)bseg * NSPLIT * DD; // bseg*2
  float* swPart = mPart + bseg * NSPLIT;                   // bseg*2
  _Float16* w1f = (_Float16*)(swPart + bseg * NSPLIT);     // 64 KB
  int* start = (int*)(w1f + 64 * 64 * 8);                  // bseg+1

  ap_setup<<<16 + (nrows + 255) / 256, 256, 0, stream>>>(W1, w1f, batch, start,
                                                         nrows, bseg);
  ap_fused<<<bseg * NSPLIT, 512, 0, stream>>>(x, w1f, b1, W2, b2, start,
                                              pooledPart, mPart, swPart, nrows);
  ap_final<<<bseg, 64, 0, stream>>>(pooledPart, mPart, swPart, start, out, nrows);
}

// Round 18
// 145.889 us; speedup vs baseline: 1.0480x; 1.0480x over previous
//
#include <hip/hip_runtime.h>
#include <math.h>

typedef float f32x4 __attribute__((ext_vector_type(4)));
typedef __attribute__((ext_vector_type(8))) _Float16 f16x8;
typedef __attribute__((ext_vector_type(4))) _Float16 f16x4;

#define DD 256
#define DH 128
#define NSPLIT 2
#define TROWS 32  // rows per block tile

// ---------------------------------------------------------------------------
// K0 (merged): blocks 0..15: W1 -> f16 MFMA B-fragment order
//   w1f[((kt*8+nt)*64+l)*8+j] = f16(W1[kt*32+(l>>4)*8+j][nt*16+(l&15)])
// blocks 16..: segment boundaries (batch sorted).
// ---------------------------------------------------------------------------
__global__ void ap_setup(const float* __restrict__ W1, _Float16* __restrict__ w1f,
                         const int* __restrict__ batch, int* __restrict__ start,
                         int nrows, int bseg) {
  const int bid = blockIdx.x;
  if (bid < 16) {
    int t = bid * 256 + threadIdx.x;  // 0..4095
    int l = t & 63;
    int tile = t >> 6;  // kt*8 + nt
    int kt = tile >> 3, nt = tile & 7;
    int kbase = kt * 32 + (l >> 4) * 8;
    int col = nt * 16 + (l & 15);
#pragma unroll
    for (int j = 0; j < 8; ++j) {
      w1f[t * 8 + j] = (_Float16)W1[(kbase + j) * DH + col];
    }
  } else {
    int i = (bid - 16) * 256 + threadIdx.x;
    if (i >= nrows) return;
    int c = batch[i];
    int p = (i == 0) ? -1 : batch[i - 1];
    for (int b = p + 1; b <= c; ++b) start[b] = i;
    if (i == nrows - 1) {
      for (int b = c + 1; b <= bseg; ++b) start[b] = nrows;
    }
  }
}

// ---------------------------------------------------------------------------
// K2: fused, block = (segment, piece). Round-16 one-barrier double-buffered
// pipeline, re-decomposed for 2 blocks/CU (4 waves/SIMD, 2x the TLP):
//  - TROWS=32; wave wv owns nt=wv (B = 8 frags = 32 VGPR, from L2 once),
//    2 row-groups for MFMA, 4 rows for load/pool (xcol+xnext = 32 VGPR).
//  - est ~100 VGPR (cap 128 via __launch_bounds__(512,2)); LDS ~35 KB
//    (2x16 KB f16 x-tiles + praw) -> two blocks fit both caps.
// Coalesced x loads (lane=chunk); f16-only MLP; pooling from live fp32
// xcol regs. Per-piece online max (shift cancels except the 1e-8 term,
// ~1e-13 rel). Deterministic: fixed-order reductions, no fp atomics.
// ---------------------------------------------------------------------------
__global__ __launch_bounds__(512, 2)
void ap_fused(const float* __restrict__ x, const _Float16* __restrict__ w1f,
              const float* __restrict__ b1, const float* __restrict__ W2,
              const float* __restrict__ b2, const int* __restrict__ start,
              float* __restrict__ pooledPart, float* __restrict__ mPart,
              float* __restrict__ swPart, int nrows) {
  __shared__ __align__(16) _Float16 xsh[2][TROWS * 256];  // 2x16 KB f16 tiles
  __shared__ float praw[2][8][TROWS];                     // 8 nt-partials/row
  __shared__ float swArr[8];

  const int tid = threadIdx.x;
  const int wv = tid >> 6;    // 0..7 ; wave's nt = wv
  const int l = tid & 63;
  const int l15 = l & 15, lhi = l >> 4;

  const int bi = blockIdx.x;
  const int b = bi >> 1;
  const int q = bi & (NSPLIT - 1);
  const int s0 = start[b], e0 = start[b + 1];
  const int cnt = e0 - s0;
  const int L = (cnt + NSPLIT - 1) >> 1;
  const int s = s0 + q * L;
  int pe = s + L;
  if (pe > e0) pe = e0;
  const int e = pe;
  const int ce = (e > 0) ? (e - 1) : 0;  // safe clamp row

  // ---- B fragments -> registers (8 frags = 32 VGPR), from L2 ----
  f16x8 Breg[8];  // [kt], this wave's nt = wv
#pragma unroll
  for (int kt = 0; kt < 8; ++kt) {
    Breg[kt] = *((const f16x8*)w1f + (size_t)(kt * 8 + wv) * 64 + l);
  }
  const float b1f = b1[wv * 16 + l15];
  const float w2f = W2[wv * 16 + l15];
  const float bb = *b2;
  const float NI = -__builtin_inff();

  f32x4 accp = {0.f, 0.f, 0.f, 0.f};  // lane-local pooled chunk (cols l*4..)
  float m = NI;
  float swv = 0.f;

  // prologue: load tile0 rows (coalesced: lane l = chunk l), cvt+write xs[0]
  f32x4 xcol[4], xnext[4];
#pragma unroll
  for (int i = 0; i < 4; ++i) {
    int grow = s + wv * 4 + i;
    if (grow > ce) grow = ce;
    if (grow < 0) grow = 0;
    xcol[i] = *(const f32x4*)(x + (size_t)grow * DD + l * 4);
  }
#pragma unroll
  for (int i = 0; i < 4; ++i) {
    const int R = wv * 4 + i;
    const int gp = l ^ ((R & 7) << 1);
    f16x4 h4;
#pragma unroll
    for (int j = 0; j < 4; ++j) h4[j] = (_Float16)xcol[i][j];
    *(f16x4*)(xsh[0] + (size_t)(R * 64 + gp) * 4) = h4;
  }
  __syncthreads();  // xs[0] ready

  int buf = 0;
  for (int t0 = s; t0 < e; t0 += TROWS) {
    const bool hasNext = (t0 + TROWS < e);

    // ---- (1) prefetch next tile rows ----
    if (hasNext) {
#pragma unroll
      for (int i = 0; i < 4; ++i) {
        int grow = t0 + TROWS + wv * 4 + i;
        if (grow > ce) grow = ce;
        xnext[i] = *(const f32x4*)(x + (size_t)grow * DD + l * 4);
      }
    }

    // ---- (2) MFMA: A from xs[buf] (2 row-groups), B from registers ----
    f32x4 acc[2];
#pragma unroll
    for (int rg2 = 0; rg2 < 2; ++rg2) acc[rg2] = f32x4{0.f, 0.f, 0.f, 0.f};
#pragma unroll
    for (int kt = 0; kt < 8; ++kt) {
#pragma unroll
      for (int rg2 = 0; rg2 < 2; ++rg2) {
        const int Rr = rg2 * 16 + l15;
        const int gp = (kt * 8 + lhi * 2) ^ ((Rr & 7) << 1);
        const f16x8 ah = *(const f16x8*)(xsh[buf] + (size_t)(Rr * 64 + gp) * 4);
        acc[rg2] =
            __builtin_amdgcn_mfma_f32_16x16x32_f16(ah, Breg[kt], acc[rg2], 0, 0, 0);
      }
    }

    // ---- (3) epilogue: relu+b1, dot W2 (wave's 16 cols), reduce l15 ----
    float pr[2][4];
#pragma unroll
    for (int rg2 = 0; rg2 < 2; ++rg2)
#pragma unroll
      for (int r = 0; r < 4; ++r)
        pr[rg2][r] = fmaxf(acc[rg2][r] + b1f, 0.f) * w2f;
#pragma unroll
    for (int mm = 1; mm < 16; mm <<= 1) {
#pragma unroll
      for (int rg2 = 0; rg2 < 2; ++rg2)
#pragma unroll
        for (int r = 0; r < 4; ++r) pr[rg2][r] += __shfl_xor(pr[rg2][r], mm, 64);
    }
    if (l15 == 0) {
#pragma unroll
      for (int rg2 = 0; rg2 < 2; ++rg2)
#pragma unroll
        for (int r = 0; r < 4; ++r)
          praw[buf][wv][rg2 * 16 + lhi * 4 + r] = pr[rg2][r];
    }

    // ---- (4) convert + write NEXT tile into xs[buf^1] (overlaps MFMA) ----
    if (hasNext) {
#pragma unroll
      for (int i = 0; i < 4; ++i) {
        const int R = wv * 4 + i;
        const int gp = l ^ ((R & 7) << 1);
        f16x4 h4;
#pragma unroll
        for (int j = 0; j < 4; ++j) h4[j] = (_Float16)xnext[i][j];
        *(f16x4*)(xsh[buf ^ 1] + (size_t)(R * 64 + gp) * 4) = h4;
      }
    }

    __syncthreads();  // (5) the ONE barrier per tile

    // ---- (6) block-uniform online softmax over the 32 tile rows ----
    const int lr = l & 31;  // lanes 32..63 duplicate rows 0..31 (max-safe)
    float tot = NI;
    if (t0 + lr < e) {
      tot = bb;
#pragma unroll
      for (int p = 0; p < 8; ++p) tot += praw[buf][p][lr];
    }
    float tv = tot;
#pragma unroll
    for (int mm = 1; mm < 64; mm <<= 1) tv = fmaxf(tv, __shfl_xor(tv, mm, 64));
    const float nm = fmaxf(m, tv);       // row t0 valid -> finite
    const float factor = expf(m - nm);   // first tile: exp(-inf) = 0
    m = nm;
    accp *= factor;
    swv *= factor;

    // ---- (7) pooling from the LIVE xcol fp32 registers (4 rows/wave) ----
#pragma unroll
    for (int i = 0; i < 4; ++i) {
      const int R = wv * 4 + i;
      const float wi = expf(__shfl(tot, R, 64) - m);  // invalid row -> 0
      swv += wi;
      accp += wi * xcol[i];
    }
#pragma unroll
    for (int i = 0; i < 4; ++i) xcol[i] = xnext[i];
    buf ^= 1;
  }

  // ---- combine 8 wave partials (m is block-uniform), write piece ----
  __syncthreads();                       // xs free; alias xsh as pooled
  float* pooled = (float*)xsh;           // 8x256 f32 = 8 KB (fits 32 KB)
  *(f32x4*)(pooled + (size_t)(wv * 256 + l * 4)) = accp;
  if (l == 0) swArr[wv] = swv;
  __syncthreads();
  if (tid < 64) {
    float sum_w = 0.f;
#pragma unroll
    for (int p = 0; p < 8; ++p) sum_w += swArr[p];
    const f32x4* pw = (const f32x4*)pooled;
    f32x4 v = ((pw[0 * 64 + tid] + pw[1 * 64 + tid]) +
               (pw[2 * 64 + tid] + pw[3 * 64 + tid]));
    f32x4 w = ((pw[4 * 64 + tid] + pw[5 * 64 + tid]) +
               (pw[6 * 64 + tid] + pw[7 * 64 + tid]));
    *(f32x4*)(pooledPart + (size_t)bi * DD + tid * 4) = v + w;
    if (tid == 0) { mPart[bi] = m; swPart[bi] = sum_w; }
  }
}

// ---------------------------------------------------------------------------
// K3: merge the NSPLIT piece partials per segment (fixed order), scale, write.
// ---------------------------------------------------------------------------
__global__ __launch_bounds__(64)
void ap_final(const float* __restrict__ pooledPart, const float* __restrict__ mPart,
              const float* __restrict__ swPart, const int* __restrict__ start,
              float* __restrict__ out, int nrows) {
  const int b = blockIdx.x;
  const int tid = threadIdx.x;
  const float NI = -__builtin_inff();
  float mq[NSPLIT];
#pragma unroll
  for (int qv = 0; qv < NSPLIT; ++qv) mq[qv] = mPart[b * NSPLIT + qv];
  float m_f = NI;
#pragma unroll
  for (int qv = 0; qv < NSPLIT; ++qv) m_f = fmaxf(m_f, mq[qv]);
  float fac[NSPLIT];
  float sum_w = 0.f;
#pragma unroll
  for (int qv = 0; qv < NSPLIT; ++qv) {
    fac[qv] = (mq[qv] == NI) ? 0.f : expf(mq[qv] - m_f);
    sum_w += swPart[b * NSPLIT + qv] * fac[qv];
  }
  const int cnt = start[b + 1] - start[b];
  const float cntf = (float)(cnt > 0 ? cnt : 1);
  const float scale = 1.0f / (((sum_w / cntf) * (float)nrows + 1e-8f) * cntf);
  f32x4 r = f32x4{0.f, 0.f, 0.f, 0.f};
#pragma unroll
  for (int qv = 0; qv < NSPLIT; ++qv) {
    r += ((const f32x4*)(pooledPart + (size_t)(b * NSPLIT + qv) * DD))[tid] * fac[qv];
  }
  r *= scale;
  *(f32x4*)(out + (size_t)b * DD + tid * 4) = r;
}

extern "C" void kernel_launch(void* const* d_in, const int* in_sizes, int n_in,
                              void* d_out, int out_size, void* d_ws, size_t ws_size,
                              hipStream_t stream) {
  const float* x     = (const float*)d_in[0];
  const int*   batch = (const int*)d_in[1];
  const float* W1    = (const float*)d_in[2];
  const float* b1    = (const float*)d_in[3];
  const float* W2    = (const float*)d_in[4];
  const float* b2    = (const float*)d_in[5];
  float* out = (float*)d_out;

  const int nrows = in_sizes[1];
  const int bseg = out_size / DD;

  // workspace layout (16B-aligned)
  float* pooledPart = (float*)d_ws;                        // bseg*2*256 f32
  float* mPart  = pooledPart + (size_t)bseg * NSPLIT * DD; // bseg*2
  float* swPart = mPart + bseg * NSPLIT;                   // bseg*2
  _Float16* w1f = (_Float16*)(swPart + bseg * NSPLIT);     // 64 KB
  int* start = (int*)(w1f + 64 * 64 * 8);                  // bseg+1

  ap_setup<<<16 + (nrows + 255) / 256, 256, 0, stream>>>(W1, w1f, batch, start,
                                                         nrows, bseg);
  ap_fused<<<bseg * NSPLIT, 512, 0, stream>>>(x, w1f, b1, W2, b2, start,
                                              pooledPart, mPart, swPart, nrows);
  ap_final<<<bseg, 64, 0, stream>>>(pooledPart, mPart, swPart, start, out, nrows);
}